// Round 4
// baseline (206.455 us; speedup 1.0000x reference)
//
#include <hip/hip_runtime.h>
#include <hip/hip_bf16.h>
#include <cstdint>
#include <cstddef>

// ---------------------------------------------------------------------------
// GraphHeterogenousCrossAttention — fused main path, f32 I/O, round 11
//
// Math (only the i=2 / graph / T=1 hetero branch matters):
//   Q   = nf @ Wnq + bnq          (Wnq = W_node@Wq folded, K=128)
//   q   = per-32-col-head softmax(Q)
//   P   = q + v                   (ratio == 1, validated r3-r9)
//   out = P @ W_out + b_out
//
// r9 post-mortem (52 us): swapped-operand mfma(B,A) verified correct; VALU
// work halved (VALUBusy 17->9.6%) but dur flat -> epilogue work was never
// the limiter.  WRITE_SIZE 64->77.8 MB, FETCH +6.2 MB: 16B/lane scattered
// stores cause partial-128B-line RFO + write amplification.  MfmaUtil 9%,
// Occupancy 31%, VGPR_Count=64 == exactly the (256,4) cap minus 64 AGPR acc
// -> latency-bound, MLP-starved, zero register headroom for pipelining.
//
// Round-11 changes (attack MLP + RFO):
//  * 32-row tiles, grid 2048: LDS union 33792 -> 16896 B (A 8704 B aliases
//    P 16896 B across existing barrier).  9 blocks/CU by LDS; acc halves to
//    [2][4] = 32 AGPR -> ~96 VGPRs of headroom under (256,4) for the
//    compiler to prefetch/pipeline K-loop frags.  Occupancy 31 -> ~50%.
//  * Non-temporal float4 output stores: no L2 read-for-ownership on the
//    64B half-line segments.  Predict FETCH -6 MB, WRITE -> ~64-68 MB.
//  * Phase-2 acc initialized with b_out (bias add for free).
// ---------------------------------------------------------------------------

typedef __attribute__((ext_vector_type(8))) short short8;
typedef __attribute__((ext_vector_type(4))) short short4v;
typedef __attribute__((ext_vector_type(4))) float floatx4;

using bf16 = __hip_bfloat16;

static constexpr int Mrows = 65536;   // B*N
static constexpr int Lcols = 256;

static __device__ __forceinline__ short f2bs(float x) {
  bf16 h = __float2bfloat16(x);
  return *reinterpret_cast<short*>(&h);
}

// ---------------------------------------------------------------------------
// Merged setup, grid = 520 blocks x 256 threads (unchanged):
//  blocks [0,256):   wnq_t[j*128 + r] = bf16(sum_l W_node[r,l] Wq[l,j]), j=b
//  blocks [256,512): wto_t[c*256 + r] = bf16(W_out[r,c]),               r=b-256
//  blocks [512,520): head h=b-512: vvec, bnq for its 32 cols
__global__ void k_setup(const float* __restrict__ W_node,
                        const float* __restrict__ Wq,
                        const float* __restrict__ W_out,
                        const float* __restrict__ energy,
                        const float* __restrict__ W_graph,
                        const float* __restrict__ b_graph,
                        const float* __restrict__ Wk,
                        const float* __restrict__ bk,
                        const float* __restrict__ Wv,
                        const float* __restrict__ bv,
                        const float* __restrict__ b_node,
                        const float* __restrict__ bq,
                        short* __restrict__ wnq_t,
                        short* __restrict__ wto_t,
                        float* __restrict__ vvec,
                        float* __restrict__ bnq) {
  const int b = blockIdx.x;
  const int t = threadIdx.x;

  if (b < 256) {
    // ---- Wnq fold (transposed store) ----
    __shared__ float wqc[256];
    const int j = b;
    wqc[t] = Wq[t * 256 + j];
    __syncthreads();
    if (t < 128) {
      const float* wr = W_node + t * 256;
      float acc = 0.f;
#pragma unroll 8
      for (int l = 0; l < 256; ++l) acc += wr[l] * wqc[l];
      wnq_t[j * 128 + t] = f2bs(acc);
    }
  } else if (b < 512) {
    // ---- W_out transpose ----
    const int r = b - 256;
    wto_t[t * 256 + r] = f2bs(W_out[r * 256 + t]);
  } else {
    // ---- head h: vvec, bnq for cols [32h, 32h+32) ----
    __shared__ float ev[32];
    __shared__ float lg[256];
    __shared__ float r1[256], r2[256];
    const int h = b - 512;
    if (t < 32) ev[t] = energy[t];
    __syncthreads();

    // lg[d] = b_graph[d] + energy @ W_graph[:,d]   (d = t)
    {
      float lgd = b_graph[t];
#pragma unroll
      for (int e = 0; e < 32; ++e) lgd += ev[e] * W_graph[e * 256 + t];
      lg[t] = lgd;
    }
    __syncthreads();

    const int g = t >> 5;          // d-group 0..7
    const int c = t & 31;          // col within head
    const int j = h * 32 + c;      // global col
    float p1 = 0.f, p2 = 0.f;
#pragma unroll
    for (int i = 0; i < 32; ++i) {
      const int d = g * 32 + i;
      p1 += lg[d] * Wv[2 * 65536 + d * 256 + j];
      p2 += b_node[d] * Wq[d * 256 + j];
    }
    r1[t] = p1; r2[t] = p2;
    __syncthreads();
    if (t < 32) {
      float s1 = 0.f, s2 = 0.f;
#pragma unroll
      for (int gg = 0; gg < 8; ++gg) {
        s1 += r1[gg * 32 + c]; s2 += r2[gg * 32 + c];
      }
      vvec[j] = s1 + bv[512 + j];
      bnq[j]  = s2 + bq[j];
    }
  }
}

// ---------------------------------------------------------------------------
// Fused: Q-GEMM (K=128) -> per-head softmax + v -> out-GEMM (K=256)
// Block: 256 threads (4 waves), tile 32 rows x 256 cols; wave w owns cols
// [64w,64w+64).  SWAPPED mfma(B,A): C layout lane&15 = tile ROW,
// (lane>>4)*4 + reg = col within the wave's 64-col slab.
// A (8704 B) and P (16896 B) alias in one LDS union across barrier (2);
// W B-frags direct global->VGPR (L2-resident).  grid = M/32, 3 barriers.
__global__ __launch_bounds__(256, 4)
void k_fused(const float* __restrict__ nf,
             const short* __restrict__ wnq,    // [256 j][128 k] bf16 bits
             const short* __restrict__ wto,    // [256 j][256 k] bf16 bits
             const float* __restrict__ bnq,
             const float* __restrict__ vvec,
             const float* __restrict__ b_out,
             float* __restrict__ out) {
  constexpr int AS_STR = 136;            // A row stride (shorts), 272 B
  constexpr int PS_STR = 264;            // P row stride (shorts), 528 B
  __shared__ short smem[32 * PS_STR];    // 16896 B union (A: first 8704 B)

  const int t = threadIdx.x;
  const int lane = t & 63;
  const int l15 = lane & 15;
  const int lhi = lane >> 4;             // quad 0..3
  const int cw = (t >> 6) * 64;          // wave col base
  const int rowBase = blockIdx.x * 32;
  const int colq = cw + lhi * 4;         // this lane's col-quad base (+n*16)

  // ---- stage A (32 rows x 128 k, f32 -> bf16), once ----
  {
    const int row = t >> 3;              // 0..31
    const int c0 = (t & 7) << 4;         // 0,16,...,112
    const float* src = nf + (size_t)(rowBase + row) * 128 + c0;
    short tmp[16];
#pragma unroll
    for (int i = 0; i < 4; ++i) {
      float4 f = *(const float4*)(src + i * 4);
      tmp[i * 4 + 0] = f2bs(f.x); tmp[i * 4 + 1] = f2bs(f.y);
      tmp[i * 4 + 2] = f2bs(f.z); tmp[i * 4 + 3] = f2bs(f.w);
    }
#pragma unroll
    for (int i = 0; i < 2; ++i)
      *(short8*)(&smem[row * AS_STR + c0 + i * 8]) = *(short8*)(&tmp[i * 8]);
  }

  // prefetch kc=0 B-frags of phase 1 (independent of LDS) + small vectors
  const short* wb1 = wnq + (cw + l15) * 128 + lhi * 8;
  short8 pbf1[4];
#pragma unroll
  for (int n = 0; n < 4; ++n) pbf1[n] = *(const short8*)(wb1 + n * 16 * 128);
  floatx4 bnq4[4], vv4[4], bo4[4];
#pragma unroll
  for (int n = 0; n < 4; ++n) {
    bnq4[n] = *(const floatx4*)(&bnq[colq + n * 16]);
    vv4[n]  = *(const floatx4*)(&vvec[colq + n * 16]);
    bo4[n]  = *(const floatx4*)(&b_out[colq + n * 16]);
  }

  __syncthreads();                       // (1) A visible

  floatx4 acc[2][4];
#pragma unroll
  for (int m = 0; m < 2; ++m)
#pragma unroll
    for (int n = 0; n < 4; ++n) acc[m][n] = (floatx4){0.f, 0.f, 0.f, 0.f};

  // ---- phase 1: Q^T frags = mfma(Wnq-frag, A-frag), K=128 ----
  {
#pragma unroll
    for (int kc = 0; kc < 4; ++kc) {
      short8 af[2], bfv[4];
#pragma unroll
      for (int n = 0; n < 4; ++n)
        bfv[n] = (kc == 0) ? pbf1[n]
                           : *(const short8*)(wb1 + n * 16 * 128 + kc * 32);
#pragma unroll
      for (int m = 0; m < 2; ++m)
        af[m] = *(const short8*)(&smem[(m * 16 + l15) * AS_STR + kc * 32 + lhi * 8]);
#pragma unroll
      for (int m = 0; m < 2; ++m)
#pragma unroll
        for (int n = 0; n < 4; ++n)
          acc[m][n] = __builtin_amdgcn_mfma_f32_16x16x32_bf16(bfv[n], af[m],
                                                              acc[m][n], 0, 0, 0);
    }
  }

  // prefetch kc=0 B-frags of phase 2 (fly during softmax)
  const short* wb2 = wto + (cw + l15) * 256 + lhi * 8;
  short8 pbf2[4];
#pragma unroll
  for (int n = 0; n < 4; ++n) pbf2[n] = *(const short8*)(wb2 + n * 16 * 256);

  __syncthreads();                       // (2) A reads done; P may overwrite

  // ---- epilogue 1: per-head softmax + v -> P (bf16, LDS) ----
  // Swapped C layout: lane holds rows m*16+l15, cols colq + n*16 + r.
  // Head tt = cols [cw+32tt, cw+32tt+32) = frags n=2tt,2tt+1; each lane has
  // 8 of the 32 cols, remaining 4x spread is over lhi -> shfl_xor 16,32.
#pragma unroll
  for (int m = 0; m < 2; ++m) {
#pragma unroll
    for (int tt = 0; tt < 2; ++tt) {
      const int n0 = 2 * tt, n1 = n0 + 1;
      float e0[4], e1[4];
#pragma unroll
      for (int r = 0; r < 4; ++r) {
        e0[r] = __expf(acc[m][n0][r] + bnq4[n0][r]);
        e1[r] = __expf(acc[m][n1][r] + bnq4[n1][r]);
      }
      float s = ((e0[0] + e0[1]) + (e0[2] + e0[3]))
              + ((e1[0] + e1[1]) + (e1[2] + e1[3]));
      s += __shfl_xor(s, 16);
      s += __shfl_xor(s, 32);
      const float inv = 1.0f / s;
      short4v p0, p1;
#pragma unroll
      for (int r = 0; r < 4; ++r) {
        p0[r] = f2bs(e0[r] * inv + vv4[n0][r]);
        p1[r] = f2bs(e1[r] * inv + vv4[n1][r]);
      }
      const int prow = (m * 16 + l15) * PS_STR;
      *(short4v*)(&smem[prow + colq + n0 * 16]) = p0;
      *(short4v*)(&smem[prow + colq + n1 * 16]) = p1;
    }
  }
  // phase-2 acc pre-loaded with bias (bias add for free)
#pragma unroll
  for (int m = 0; m < 2; ++m)
#pragma unroll
    for (int n = 0; n < 4; ++n) acc[m][n] = bo4[n];
  __syncthreads();                       // (3) P visible to all waves

  // ---- phase 2: out^T frags = mfma(Wout-frag, P-frag), K=256 ----
  {
#pragma unroll
    for (int kc = 0; kc < 8; ++kc) {
      short8 af[2], bfv[4];
#pragma unroll
      for (int n = 0; n < 4; ++n)
        bfv[n] = (kc == 0) ? pbf2[n]
                           : *(const short8*)(wb2 + n * 16 * 256 + kc * 32);
#pragma unroll
      for (int m = 0; m < 2; ++m)
        af[m] = *(const short8*)(&smem[(m * 16 + l15) * PS_STR + kc * 32 + lhi * 8]);
#pragma unroll
      for (int m = 0; m < 2; ++m)
#pragma unroll
        for (int n = 0; n < 4; ++n)
          acc[m][n] = __builtin_amdgcn_mfma_f32_16x16x32_bf16(bfv[n], af[m],
                                                              acc[m][n], 0, 0, 0);
    }
  }

  // ---- epilogue 2: direct non-temporal stores (no RFO on 64B segments) ----
#pragma unroll
  for (int m = 0; m < 2; ++m) {
    const size_t rbase = (size_t)(rowBase + m * 16 + l15) * Lcols;
#pragma unroll
    for (int n = 0; n < 4; ++n) {
      __builtin_nontemporal_store(acc[m][n],
                                  (floatx4*)(&out[rbase + colq + n * 16]));
    }
  }
}

// ---------------------------------------------------------------------------
extern "C" void kernel_launch(void* const* d_in, const int* in_sizes, int n_in,
                              void* d_out, int out_size, void* d_ws, size_t ws_size,
                              hipStream_t stream) {
  const float* node_features = (const float*)d_in[0];
  // d_in[1] edge_features: dead code
  const float* energy  = (const float*)d_in[2];
  const float* W_node  = (const float*)d_in[3];
  const float* b_node  = (const float*)d_in[4];
  // d_in[5,6] W_edge/b_edge: dead code
  const float* W_graph = (const float*)d_in[7];
  const float* b_graph = (const float*)d_in[8];
  const float* Wq      = (const float*)d_in[9];
  const float* bq      = (const float*)d_in[10];
  const float* Wk      = (const float*)d_in[11];
  const float* bk      = (const float*)d_in[12];
  const float* Wv      = (const float*)d_in[13];
  const float* bv      = (const float*)d_in[14];
  const float* W_out   = (const float*)d_in[15];
  const float* b_out   = (const float*)d_in[16];

  // workspace: tables only (< 256 KB)
  char* ws = (char*)d_ws;
  short* wnq_t = (short*)(ws);                  // 256*128*2 = 65536 B
  short* wto_t = (short*)(ws + 65536);          // 256*256*2 = 131072 B
  float* vvec  = (float*)(ws + 196608);         // 1 KB
  float* bnq   = (float*)(ws + 197632);         // 1 KB

  k_setup<<<dim3(520), dim3(256), 0, stream>>>(
      W_node, Wq, W_out, energy, W_graph, b_graph, Wk, bk, Wv, bv,
      b_node, bq, wnq_t, wto_t, vvec, bnq);

  k_fused<<<dim3(Mrows / 32), dim3(256), 0, stream>>>(
      node_features, wnq_t, wto_t, bnq, vvec, b_out, (float*)d_out);
}

// Round 5
// 202.359 us; speedup vs baseline: 1.0202x; 1.0202x over previous
//
#include <hip/hip_runtime.h>
#include <hip/hip_bf16.h>
#include <cstdint>
#include <cstddef>

// ---------------------------------------------------------------------------
// GraphHeterogenousCrossAttention — fused main path, f32 I/O, round 12
//
// Math (only the i=2 / graph / T=1 hetero branch matters):
//   Q   = nf @ Wnq + bnq          (Wnq = W_node@Wq folded, K=128)
//   q   = per-32-col-head softmax(Q)
//   P   = q + v                   (ratio == 1, validated r3-r11)
//   out = P @ W_out + b_out
//
// History: r7 49us (staged A, LDS bounce stores, 64MB writes exact);
// r9 52us (swapped mfma(B,A), reg softmax, direct 16B stores -> +14MB RFO);
// r11 66us REGRESSION (32-row tiles: occupancy did NOT rise - resident
// waves stuck ~11/CU regardless of LDS; smaller tiles just doubled the
// latency-bound cold starts.  nt-stores fixed FETCH (-6MB) not WRITE).
//
// Round-12 theory: latency-bound everywhere (all pipes <10%, HBM 20%);
// shorten the per-block critical path:
//  * 64-row tiles restored (grid 1024).
//  * A-STAGING DELETED: phase-1 A-frags load straight from nf (32B/lane,
//    one frag instruction = 16 full 128B lines, perfectly coalesced) with
//    in-register f32->bf16 convert.  Kills the stage loop, the LDS
//    round-trip, and the two front barriers -> block never syncs on the
//    slowest HBM load; per-wave VMEM fully independent (deep MLP).
//    Cost: each nf element converted by all 4 waves (~+400 VALU cyc/wave,
//    cheap at 8% VALUBusy).
//  * r7's f32 LDS-bounce + per-wave 1KB-burst store epilogue restored
//    (adapted to swapped layout) -- the only store path measuring exactly
//    64MB WRITE_SIZE.
//  * Swapped-operand MFMA + register softmax kept (r9's VALU win).
// Predicted: WRITE 73.8->64MB, FETCH ~17MB, dur 52 -> 40-45us.
// Falsifier: dur ~= 49-52 with writes fixed => concurrency cap is
// structural -> go persistent-block next.
// ---------------------------------------------------------------------------

typedef __attribute__((ext_vector_type(8))) short short8;
typedef __attribute__((ext_vector_type(4))) short short4v;
typedef __attribute__((ext_vector_type(4))) float floatx4;

using bf16 = __hip_bfloat16;

static constexpr int Mrows = 65536;   // B*N
static constexpr int Lcols = 256;

static __device__ __forceinline__ short f2bs(float x) {
  bf16 h = __float2bfloat16(x);
  return *reinterpret_cast<short*>(&h);
}

// ---------------------------------------------------------------------------
// Merged setup, grid = 520 blocks x 256 threads (unchanged):
//  blocks [0,256):   wnq_t[j*128 + r] = bf16(sum_l W_node[r,l] Wq[l,j]), j=b
//  blocks [256,512): wto_t[c*256 + r] = bf16(W_out[r,c]),               r=b-256
//  blocks [512,520): head h=b-512: vvec, bnq for its 32 cols
__global__ void k_setup(const float* __restrict__ W_node,
                        const float* __restrict__ Wq,
                        const float* __restrict__ W_out,
                        const float* __restrict__ energy,
                        const float* __restrict__ W_graph,
                        const float* __restrict__ b_graph,
                        const float* __restrict__ Wk,
                        const float* __restrict__ bk,
                        const float* __restrict__ Wv,
                        const float* __restrict__ bv,
                        const float* __restrict__ b_node,
                        const float* __restrict__ bq,
                        short* __restrict__ wnq_t,
                        short* __restrict__ wto_t,
                        float* __restrict__ vvec,
                        float* __restrict__ bnq) {
  const int b = blockIdx.x;
  const int t = threadIdx.x;

  if (b < 256) {
    // ---- Wnq fold (transposed store) ----
    __shared__ float wqc[256];
    const int j = b;
    wqc[t] = Wq[t * 256 + j];
    __syncthreads();
    if (t < 128) {
      const float* wr = W_node + t * 256;
      float acc = 0.f;
#pragma unroll 8
      for (int l = 0; l < 256; ++l) acc += wr[l] * wqc[l];
      wnq_t[j * 128 + t] = f2bs(acc);
    }
  } else if (b < 512) {
    // ---- W_out transpose ----
    const int r = b - 256;
    wto_t[t * 256 + r] = f2bs(W_out[r * 256 + t]);
  } else {
    // ---- head h: vvec, bnq for cols [32h, 32h+32) ----
    __shared__ float ev[32];
    __shared__ float lg[256];
    __shared__ float r1[256], r2[256];
    const int h = b - 512;
    if (t < 32) ev[t] = energy[t];
    __syncthreads();

    // lg[d] = b_graph[d] + energy @ W_graph[:,d]   (d = t)
    {
      float lgd = b_graph[t];
#pragma unroll
      for (int e = 0; e < 32; ++e) lgd += ev[e] * W_graph[e * 256 + t];
      lg[t] = lgd;
    }
    __syncthreads();

    const int g = t >> 5;          // d-group 0..7
    const int c = t & 31;          // col within head
    const int j = h * 32 + c;      // global col
    float p1 = 0.f, p2 = 0.f;
#pragma unroll
    for (int i = 0; i < 32; ++i) {
      const int d = g * 32 + i;
      p1 += lg[d] * Wv[2 * 65536 + d * 256 + j];
      p2 += b_node[d] * Wq[d * 256 + j];
    }
    r1[t] = p1; r2[t] = p2;
    __syncthreads();
    if (t < 32) {
      float s1 = 0.f, s2 = 0.f;
#pragma unroll
      for (int gg = 0; gg < 8; ++gg) {
        s1 += r1[gg * 32 + c]; s2 += r2[gg * 32 + c];
      }
      vvec[j] = s1 + bv[512 + j];
      bnq[j]  = s2 + bq[j];
    }
  }
}

// ---------------------------------------------------------------------------
// Fused: Q-GEMM (K=128, A direct from global) -> reg softmax + v -> P (LDS)
// -> out-GEMM (K=256) -> f32 LDS bounce -> 1KB-burst stores.
// Block: 256 threads (4 waves), tile 64 rows x 256 cols; wave w owns cols
// [64w,64w+64).  SWAPPED mfma(B,A): C layout lane&15 = tile ROW,
// (lane>>4)*4 + reg = col within the wave's 64-col slab.
// P (bf16) and the f32 bounce tile share one LDS union.  grid = M/64.
__global__ __launch_bounds__(256, 4)
void k_fused(const float* __restrict__ nf,
             const short* __restrict__ wnq,    // [256 j][128 k] bf16 bits
             const short* __restrict__ wto,    // [256 j][256 k] bf16 bits
             const float* __restrict__ bnq,
             const float* __restrict__ vvec,
             const float* __restrict__ b_out,
             float* __restrict__ out) {
  constexpr int PS_STR = 264;            // P row stride (shorts), 528 B
  constexpr int FO_STR = 260;            // bounce row stride (floats), 1040 B
  __shared__ short smem[64 * PS_STR];    // 33792 B union (f32 bounce 33280 B)
  float* fsm = (float*)smem;

  const int t = threadIdx.x;
  const int lane = t & 63;
  const int l15 = lane & 15;
  const int lhi = lane >> 4;             // quad 0..3
  const int cw = (t >> 6) * 64;          // wave col base
  const int rowBase = blockIdx.x * 64;
  const int colq = cw + lhi * 4;         // this lane's col-quad base (+n*16)

  // per-lane A source: row (m*16+l15), k-slice (kc*32 + lhi*8)
  const float* abase = nf + (size_t)(rowBase + l15) * 128 + lhi * 8;

  // B-frag base pointers + small vectors
  const short* wb1 = wnq + (cw + l15) * 128 + lhi * 8;
  const short* wb2 = wto + (cw + l15) * 256 + lhi * 8;
  floatx4 bnq4[4], vv4[4], bo4[4];
#pragma unroll
  for (int n = 0; n < 4; ++n) {
    bnq4[n] = *(const floatx4*)(&bnq[colq + n * 16]);
    vv4[n]  = *(const floatx4*)(&vvec[colq + n * 16]);
    bo4[n]  = *(const floatx4*)(&b_out[colq + n * 16]);
  }

  floatx4 acc[4][4];
#pragma unroll
  for (int m = 0; m < 4; ++m)
#pragma unroll
    for (int n = 0; n < 4; ++n) acc[m][n] = (floatx4){0.f, 0.f, 0.f, 0.f};

  // ---- phase 1: Q^T frags = mfma(Wnq-frag, A-frag), K=128 ----
  // A-frags straight from global: per (m,kc) one 32B read/lane; the wave's
  // 64 lanes cover 16 full 128B lines.  No LDS, no barrier.
  {
#pragma unroll
    for (int kc = 0; kc < 4; ++kc) {
      short8 af[4], bfv[4];
#pragma unroll
      for (int n = 0; n < 4; ++n)
        bfv[n] = *(const short8*)(wb1 + n * 16 * 128 + kc * 32);
#pragma unroll
      for (int m = 0; m < 4; ++m) {
        const float* ap = abase + m * 16 * 128 + kc * 32;
        float4 f0 = *(const float4*)(ap);
        float4 f1 = *(const float4*)(ap + 4);
        af[m][0] = f2bs(f0.x); af[m][1] = f2bs(f0.y);
        af[m][2] = f2bs(f0.z); af[m][3] = f2bs(f0.w);
        af[m][4] = f2bs(f1.x); af[m][5] = f2bs(f1.y);
        af[m][6] = f2bs(f1.z); af[m][7] = f2bs(f1.w);
      }
#pragma unroll
      for (int m = 0; m < 4; ++m)
#pragma unroll
        for (int n = 0; n < 4; ++n)
          acc[m][n] = __builtin_amdgcn_mfma_f32_16x16x32_bf16(bfv[n], af[m],
                                                              acc[m][n], 0, 0, 0);
    }
  }

  // prefetch kc=0 B-frags of phase 2 (fly during softmax)
  short8 pbf2[4];
#pragma unroll
  for (int n = 0; n < 4; ++n) pbf2[n] = *(const short8*)(wb2 + n * 16 * 256);

  // ---- epilogue 1: per-head softmax + v -> P (bf16, LDS) ----
  // Lane holds rows m*16+l15, cols colq + n*16 + r.  Head tt = frags
  // n=2tt,2tt+1: 8 of 32 cols in-lane, 4x spread over lhi -> shfl 16,32.
#pragma unroll
  for (int m = 0; m < 4; ++m) {
#pragma unroll
    for (int tt = 0; tt < 2; ++tt) {
      const int n0 = 2 * tt, n1 = n0 + 1;
      float e0[4], e1[4];
#pragma unroll
      for (int r = 0; r < 4; ++r) {
        e0[r] = __expf(acc[m][n0][r] + bnq4[n0][r]);
        e1[r] = __expf(acc[m][n1][r] + bnq4[n1][r]);
      }
      float s = ((e0[0] + e0[1]) + (e0[2] + e0[3]))
              + ((e1[0] + e1[1]) + (e1[2] + e1[3]));
      s += __shfl_xor(s, 16);
      s += __shfl_xor(s, 32);
      const float inv = 1.0f / s;
      short4v p0, p1;
#pragma unroll
      for (int r = 0; r < 4; ++r) {
        p0[r] = f2bs(e0[r] * inv + vv4[n0][r]);
        p1[r] = f2bs(e1[r] * inv + vv4[n1][r]);
      }
      const int prow = (m * 16 + l15) * PS_STR;
      *(short4v*)(&smem[prow + colq + n0 * 16]) = p0;
      *(short4v*)(&smem[prow + colq + n1 * 16]) = p1;
    }
  }
  // phase-2 acc pre-loaded with bias (bias add for free)
#pragma unroll
  for (int m = 0; m < 4; ++m)
#pragma unroll
    for (int n = 0; n < 4; ++n) acc[m][n] = bo4[n];
  __syncthreads();                       // (1) P visible to all waves

  // ---- phase 2: out^T frags = mfma(Wout-frag, P-frag), K=256 ----
  {
#pragma unroll
    for (int kc = 0; kc < 8; ++kc) {
      short8 af[4], bfv[4];
#pragma unroll
      for (int n = 0; n < 4; ++n)
        bfv[n] = (kc == 0) ? pbf2[n]
                           : *(const short8*)(wb2 + n * 16 * 256 + kc * 32);
#pragma unroll
      for (int m = 0; m < 4; ++m)
        af[m] = *(const short8*)(&smem[(m * 16 + l15) * PS_STR + kc * 32 + lhi * 8]);
#pragma unroll
      for (int m = 0; m < 4; ++m)
#pragma unroll
        for (int n = 0; n < 4; ++n)
          acc[m][n] = __builtin_amdgcn_mfma_f32_16x16x32_bf16(bfv[n], af[m],
                                                              acc[m][n], 0, 0, 0);
    }
  }

  // ---- epilogue 2: f32 LDS bounce -> per-wave contiguous 1KB bursts ----
  // (r7's store path: the only one measuring exactly 64MB WRITE_SIZE)
#pragma unroll
  for (int c = 0; c < 2; ++c) {
    __syncthreads();                     // c=0: all P reads done; c=1:
                                         // chunk-0 LDS reads done
#pragma unroll
    for (int mm = 0; mm < 2; ++mm) {
      const int m = c * 2 + mm;
      const int frow = (mm * 16 + l15) * FO_STR;
#pragma unroll
      for (int n = 0; n < 4; ++n)
        *(floatx4*)(&fsm[frow + colq + n * 16]) = acc[m][n];
    }
    __syncthreads();
    // 32 rows x 256 f32 = 2048 float4, 8 per thread; per-wave 1KB bursts.
#pragma unroll
    for (int i = 0; i < 8; ++i) {
      const int f = i * 256 + t;
      const int row = f >> 6;
      const int c4 = (f & 63) << 2;
      float4 vv = *(const float4*)(&fsm[row * FO_STR + c4]);
      *(float4*)(&out[(size_t)(rowBase + c * 32 + row) * Lcols + c4]) = vv;
    }
  }
}

// ---------------------------------------------------------------------------
extern "C" void kernel_launch(void* const* d_in, const int* in_sizes, int n_in,
                              void* d_out, int out_size, void* d_ws, size_t ws_size,
                              hipStream_t stream) {
  const float* node_features = (const float*)d_in[0];
  // d_in[1] edge_features: dead code
  const float* energy  = (const float*)d_in[2];
  const float* W_node  = (const float*)d_in[3];
  const float* b_node  = (const float*)d_in[4];
  // d_in[5,6] W_edge/b_edge: dead code
  const float* W_graph = (const float*)d_in[7];
  const float* b_graph = (const float*)d_in[8];
  const float* Wq      = (const float*)d_in[9];
  const float* bq      = (const float*)d_in[10];
  const float* Wk      = (const float*)d_in[11];
  const float* bk      = (const float*)d_in[12];
  const float* Wv      = (const float*)d_in[13];
  const float* bv      = (const float*)d_in[14];
  const float* W_out   = (const float*)d_in[15];
  const float* b_out   = (const float*)d_in[16];

  // workspace: tables only (< 256 KB)
  char* ws = (char*)d_ws;
  short* wnq_t = (short*)(ws);                  // 256*128*2 = 65536 B
  short* wto_t = (short*)(ws + 65536);          // 256*256*2 = 131072 B
  float* vvec  = (float*)(ws + 196608);         // 1 KB
  float* bnq   = (float*)(ws + 197632);         // 1 KB

  k_setup<<<dim3(520), dim3(256), 0, stream>>>(
      W_node, Wq, W_out, energy, W_graph, b_graph, Wk, bk, Wv, bv,
      b_node, bq, wnq_t, wto_t, vvec, bnq);

  k_fused<<<dim3(Mrows / 64), dim3(256), 0, stream>>>(
      node_features, wnq_t, wto_t, bnq, vvec, b_out, (float*)d_out);
}

// Round 9
// 185.827 us; speedup vs baseline: 1.1110x; 1.0890x over previous
//
#include <hip/hip_runtime.h>
#include <hip/hip_bf16.h>
#include <cstdint>
#include <cstddef>

// ---------------------------------------------------------------------------
// GraphHeterogenousCrossAttention — fused main path, f32 I/O, round 13
// (round-16 submission: identical resubmit x3 — rounds 13/14/15 all hit
//  GPUAcquisitionTimeout, never executed; single-variable ILP experiment,
//  must run in isolation to keep its discriminating power.)
//
// Math (only the i=2 / graph / T=1 hetero branch matters):
//   Q   = nf @ Wnq + bnq          (Wnq = W_node@Wq folded, K=128)
//   q   = per-32-col-head softmax(Q)
//   P   = q + v                   (ratio == 1, validated r3-r12)
//   out = P @ W_out + b_out
//
// History: r7 49us BEST (staged A, bounce stores, WRITE=64MB exact);
// r9 52us (swapped mfma(B,A) verified, direct stores +14MB RFO);
// r11 66us (32-row tiles: occupancy flat, latency-bound cold starts x2);
// r12 60us (direct-A: FETCH +9.6MB — L2 did NOT absorb 4-wave re-read;
//           WRITE 85MB — read-pressure evicts partial out lines).
// => A-staging through LDS is load-bearing; r7 structure is the optimum
//    under perturbation.  All pipes <10%, BW pinned 1.4-2 TB/s.
// Note: bench dur_us ~= k_fused + ~140us constant (harness/graph overhead,
// invariant across edits); k_fused is the controllable objective.
//
// r13 theory: VGPR_Count=64 + 64 AGPR acc == exactly the 128-reg cap of
// __launch_bounds__(256,4) -> compiler cannot hoist loads; every frag load
// is issue->wait->use serialized (~1 VMEM in flight/wave).  Trade TLP for
// ILP: (256,2) gives 256 regs/wave; hand-prefetch ALL 16 phase-1 B-frags
// during stage-A and first 2 kc of phase-2 B-frags during softmax
// -> ~24 VMEM in flight/wave.  Keep r7's staged-A + bounce-store structure
// and r9's verified swapped-operand epilogue (cheaper softmax).
//
// Predicted: VGPR ~180-220 (no scratch!), occupancy ~25%, FETCH ~17MB,
// WRITE 65536KB exact, dur 49 -> 38-43us.
// Falsifier: dur >= 49 with high VGPR/no-spill => ILP theory dead, convoy
// effect is the limiter -> persistent double-buffered pipeline next.
// ---------------------------------------------------------------------------

typedef __attribute__((ext_vector_type(8))) short short8;
typedef __attribute__((ext_vector_type(4))) short short4v;
typedef __attribute__((ext_vector_type(4))) float floatx4;

using bf16 = __hip_bfloat16;

static constexpr int Mrows = 65536;   // B*N
static constexpr int Lcols = 256;

static __device__ __forceinline__ short f2bs(float x) {
  bf16 h = __float2bfloat16(x);
  return *reinterpret_cast<short*>(&h);
}

// ---------------------------------------------------------------------------
// Merged setup, grid = 520 blocks x 256 threads (unchanged):
//  blocks [0,256):   wnq_t[j*128 + r] = bf16(sum_l W_node[r,l] Wq[l,j]), j=b
//  blocks [256,512): wto_t[c*256 + r] = bf16(W_out[r,c]),               r=b-256
//  blocks [512,520): head h=b-512: vvec, bnq for its 32 cols
__global__ void k_setup(const float* __restrict__ W_node,
                        const float* __restrict__ Wq,
                        const float* __restrict__ W_out,
                        const float* __restrict__ energy,
                        const float* __restrict__ W_graph,
                        const float* __restrict__ b_graph,
                        const float* __restrict__ Wk,
                        const float* __restrict__ bk,
                        const float* __restrict__ Wv,
                        const float* __restrict__ bv,
                        const float* __restrict__ b_node,
                        const float* __restrict__ bq,
                        short* __restrict__ wnq_t,
                        short* __restrict__ wto_t,
                        float* __restrict__ vvec,
                        float* __restrict__ bnq) {
  const int b = blockIdx.x;
  const int t = threadIdx.x;

  if (b < 256) {
    // ---- Wnq fold (transposed store) ----
    __shared__ float wqc[256];
    const int j = b;
    wqc[t] = Wq[t * 256 + j];
    __syncthreads();
    if (t < 128) {
      const float* wr = W_node + t * 256;
      float acc = 0.f;
#pragma unroll 8
      for (int l = 0; l < 256; ++l) acc += wr[l] * wqc[l];
      wnq_t[j * 128 + t] = f2bs(acc);
    }
  } else if (b < 512) {
    // ---- W_out transpose ----
    const int r = b - 256;
    wto_t[t * 256 + r] = f2bs(W_out[r * 256 + t]);
  } else {
    // ---- head h: vvec, bnq for cols [32h, 32h+32) ----
    __shared__ float ev[32];
    __shared__ float lg[256];
    __shared__ float r1[256], r2[256];
    const int h = b - 512;
    if (t < 32) ev[t] = energy[t];
    __syncthreads();

    // lg[d] = b_graph[d] + energy @ W_graph[:,d]   (d = t)
    {
      float lgd = b_graph[t];
#pragma unroll
      for (int e = 0; e < 32; ++e) lgd += ev[e] * W_graph[e * 256 + t];
      lg[t] = lgd;
    }
    __syncthreads();

    const int g = t >> 5;          // d-group 0..7
    const int c = t & 31;          // col within head
    const int j = h * 32 + c;      // global col
    float p1 = 0.f, p2 = 0.f;
#pragma unroll
    for (int i = 0; i < 32; ++i) {
      const int d = g * 32 + i;
      p1 += lg[d] * Wv[2 * 65536 + d * 256 + j];
      p2 += b_node[d] * Wq[d * 256 + j];
    }
    r1[t] = p1; r2[t] = p2;
    __syncthreads();
    if (t < 32) {
      float s1 = 0.f, s2 = 0.f;
#pragma unroll
      for (int gg = 0; gg < 8; ++gg) {
        s1 += r1[gg * 32 + c]; s2 += r2[gg * 32 + c];
      }
      vvec[j] = s1 + bv[512 + j];
      bnq[j]  = s2 + bq[j];
    }
  }
}

// ---------------------------------------------------------------------------
// Fused: Q-GEMM (K=128) -> reg softmax + v -> P (LDS) -> out-GEMM (K=256)
// -> f32 LDS bounce -> per-wave 1KB-burst stores.
// Block: 256 threads (4 waves), tile 64 rows x 256 cols; wave w owns cols
// [64w,64w+64).  SWAPPED mfma(B,A): C layout lane&15 = tile ROW,
// (lane>>4)*4 + reg = col within the wave's 64-col slab.
// A (17408 B) / P (33792 B) / f32 bounce (33280 B) share one LDS union.
// (256,2): 256 regs/wave -> deep hand-prefetch ILP.  grid = M/64.
__global__ __launch_bounds__(256, 2)
void k_fused(const float* __restrict__ nf,
             const short* __restrict__ wnq,    // [256 j][128 k] bf16 bits
             const short* __restrict__ wto,    // [256 j][256 k] bf16 bits
             const float* __restrict__ bnq,
             const float* __restrict__ vvec,
             const float* __restrict__ b_out,
             float* __restrict__ out) {
  constexpr int AS_STR = 136;            // A row stride (shorts), 272 B
  constexpr int PS_STR = 264;            // P row stride (shorts), 528 B
  constexpr int FO_STR = 260;            // bounce row stride (floats), 1040 B
  __shared__ short smem[64 * PS_STR];    // 33792 B union (A: first 17408 B)
  float* fsm = (float*)smem;

  const int t = threadIdx.x;
  const int lane = t & 63;
  const int l15 = lane & 15;
  const int lhi = lane >> 4;             // quad 0..3
  const int cw = (t >> 6) * 64;          // wave col base
  const int rowBase = blockIdx.x * 64;
  const int colq = cw + lhi * 4;         // this lane's col-quad base (+n*16)

  const short* wb1 = wnq + (cw + l15) * 128 + lhi * 8;
  const short* wb2 = wto + (cw + l15) * 256 + lhi * 8;

  // ---- stage A (64 rows x 128 k, f32 -> bf16), once ----
  {
    const int row = t >> 2;
    const int c0 = (t & 3) << 5;         // 0,32,64,96
    const float* src = nf + (size_t)(rowBase + row) * 128 + c0;
    short tmp[32];
#pragma unroll
    for (int i = 0; i < 8; ++i) {
      float4 f = *(const float4*)(src + i * 4);
      tmp[i * 4 + 0] = f2bs(f.x); tmp[i * 4 + 1] = f2bs(f.y);
      tmp[i * 4 + 2] = f2bs(f.z); tmp[i * 4 + 3] = f2bs(f.w);
    }
#pragma unroll
    for (int i = 0; i < 4; ++i)
      *(short8*)(&smem[row * AS_STR + c0 + i * 8]) = *(short8*)(&tmp[i * 8]);
  }

  // ---- prefetch ALL phase-1 B-frags (16 x short8 = 64 VGPR) while the
  //      stage-A LDS writes and other waves drain; L2-resident weights ----
  short8 pbf1[4][4];
#pragma unroll
  for (int kc = 0; kc < 4; ++kc)
#pragma unroll
    for (int n = 0; n < 4; ++n)
      pbf1[kc][n] = *(const short8*)(wb1 + n * 16 * 128 + kc * 32);

  __syncthreads();                       // (1) A visible

  floatx4 acc[4][4];
#pragma unroll
  for (int m = 0; m < 4; ++m)
#pragma unroll
    for (int n = 0; n < 4; ++n) acc[m][n] = (floatx4){0.f, 0.f, 0.f, 0.f};

  // ---- phase 1: Q^T frags = mfma(Wnq-frag, A-frag), K=128 ----
  {
#pragma unroll
    for (int kc = 0; kc < 4; ++kc) {
      short8 af[4];
#pragma unroll
      for (int m = 0; m < 4; ++m)
        af[m] = *(const short8*)(&smem[(m * 16 + l15) * AS_STR + kc * 32 + lhi * 8]);
#pragma unroll
      for (int m = 0; m < 4; ++m)
#pragma unroll
        for (int n = 0; n < 4; ++n)
          acc[m][n] = __builtin_amdgcn_mfma_f32_16x16x32_bf16(pbf1[kc][n], af[m],
                                                              acc[m][n], 0, 0, 0);
    }
  }

  // prefetch kc=0,1 B-frags of phase 2 (8 x short8) + softmax vectors
  short8 pbf2[2][4];
#pragma unroll
  for (int kc = 0; kc < 2; ++kc)
#pragma unroll
    for (int n = 0; n < 4; ++n)
      pbf2[kc][n] = *(const short8*)(wb2 + n * 16 * 256 + kc * 32);
  floatx4 bnq4[4], vv4[4];
#pragma unroll
  for (int n = 0; n < 4; ++n) {
    bnq4[n] = *(const floatx4*)(&bnq[colq + n * 16]);
    vv4[n]  = *(const floatx4*)(&vvec[colq + n * 16]);
  }

  __syncthreads();                       // (2) A reads done; P may overwrite

  // ---- epilogue 1: per-head softmax + v -> P (bf16, LDS) ----
  // Lane holds rows m*16+l15, cols colq + n*16 + r.  Head tt = frags
  // n=2tt,2tt+1: 8 of 32 cols in-lane, 4x spread over lhi -> shfl 16,32.
#pragma unroll
  for (int m = 0; m < 4; ++m) {
#pragma unroll
    for (int tt = 0; tt < 2; ++tt) {
      const int n0 = 2 * tt, n1 = n0 + 1;
      float e0[4], e1[4];
#pragma unroll
      for (int r = 0; r < 4; ++r) {
        e0[r] = __expf(acc[m][n0][r] + bnq4[n0][r]);
        e1[r] = __expf(acc[m][n1][r] + bnq4[n1][r]);
      }
      float s = ((e0[0] + e0[1]) + (e0[2] + e0[3]))
              + ((e1[0] + e1[1]) + (e1[2] + e1[3]));
      s += __shfl_xor(s, 16);
      s += __shfl_xor(s, 32);
      const float inv = 1.0f / s;
      short4v p0, p1;
#pragma unroll
      for (int r = 0; r < 4; ++r) {
        p0[r] = f2bs(e0[r] * inv + vv4[n0][r]);
        p1[r] = f2bs(e1[r] * inv + vv4[n1][r]);
      }
      const int prow = (m * 16 + l15) * PS_STR;
      *(short4v*)(&smem[prow + colq + n0 * 16]) = p0;
      *(short4v*)(&smem[prow + colq + n1 * 16]) = p1;
    }
  }
  // phase-2 acc pre-loaded with bias (free bias add)
  floatx4 bo4[4];
#pragma unroll
  for (int n = 0; n < 4; ++n) bo4[n] = *(const floatx4*)(&b_out[colq + n * 16]);
#pragma unroll
  for (int m = 0; m < 4; ++m)
#pragma unroll
    for (int n = 0; n < 4; ++n) acc[m][n] = bo4[n];
  __syncthreads();                       // (3) P visible to all waves

  // ---- phase 2: out^T frags = mfma(Wout-frag, P-frag), K=256 ----
  {
#pragma unroll
    for (int kc = 0; kc < 8; ++kc) {
      short8 af[4], bfv[4];
#pragma unroll
      for (int n = 0; n < 4; ++n)
        bfv[n] = (kc < 2) ? pbf2[kc][n]
                          : *(const short8*)(wb2 + n * 16 * 256 + kc * 32);
#pragma unroll
      for (int m = 0; m < 4; ++m)
        af[m] = *(const short8*)(&smem[(m * 16 + l15) * PS_STR + kc * 32 + lhi * 8]);
#pragma unroll
      for (int m = 0; m < 4; ++m)
#pragma unroll
        for (int n = 0; n < 4; ++n)
          acc[m][n] = __builtin_amdgcn_mfma_f32_16x16x32_bf16(bfv[n], af[m],
                                                              acc[m][n], 0, 0, 0);
    }
  }

  // ---- epilogue 2: f32 LDS bounce -> per-wave contiguous 1KB bursts ----
  // (r7's store path: the only one measuring exactly 64MB WRITE_SIZE)
#pragma unroll
  for (int c = 0; c < 2; ++c) {
    __syncthreads();                     // c=0: all P reads done; c=1:
                                         // chunk-0 LDS reads done
#pragma unroll
    for (int mm = 0; mm < 2; ++mm) {
      const int m = c * 2 + mm;
      const int frow = (mm * 16 + l15) * FO_STR;
#pragma unroll
      for (int n = 0; n < 4; ++n)
        *(floatx4*)(&fsm[frow + colq + n * 16]) = acc[m][n];
    }
    __syncthreads();
    // 32 rows x 256 f32 = 2048 float4, 8 per thread; per-wave 1KB bursts.
#pragma unroll
    for (int i = 0; i < 8; ++i) {
      const int f = i * 256 + t;
      const int row = f >> 6;
      const int c4 = (f & 63) << 2;
      float4 vv = *(const float4*)(&fsm[row * FO_STR + c4]);
      *(float4*)(&out[(size_t)(rowBase + c * 32 + row) * Lcols + c4]) = vv;
    }
  }
}

// ---------------------------------------------------------------------------
extern "C" void kernel_launch(void* const* d_in, const int* in_sizes, int n_in,
                              void* d_out, int out_size, void* d_ws, size_t ws_size,
                              hipStream_t stream) {
  const float* node_features = (const float*)d_in[0];
  // d_in[1] edge_features: dead code
  const float* energy  = (const float*)d_in[2];
  const float* W_node  = (const float*)d_in[3];
  const float* b_node  = (const float*)d_in[4];
  // d_in[5,6] W_edge/b_edge: dead code
  const float* W_graph = (const float*)d_in[7];
  const float* b_graph = (const float*)d_in[8];
  const float* Wq      = (const float*)d_in[9];
  const float* bq      = (const float*)d_in[10];
  const float* Wk      = (const float*)d_in[11];
  const float* bk      = (const float*)d_in[12];
  const float* Wv      = (const float*)d_in[13];
  const float* bv      = (const float*)d_in[14];
  const float* W_out   = (const float*)d_in[15];
  const float* b_out   = (const float*)d_in[16];

  // workspace: tables only (< 256 KB)
  char* ws = (char*)d_ws;
  short* wnq_t = (short*)(ws);                  // 256*128*2 = 65536 B
  short* wto_t = (short*)(ws + 65536);          // 256*256*2 = 131072 B
  float* vvec  = (float*)(ws + 196608);         // 1 KB
  float* bnq   = (float*)(ws + 197632);         // 1 KB

  k_setup<<<dim3(520), dim3(256), 0, stream>>>(
      W_node, Wq, W_out, energy, W_graph, b_graph, Wk, bk, Wv, bv,
      b_node, bq, wnq_t, wto_t, vvec, bnq);

  k_fused<<<dim3(Mrows / 64), dim3(256), 0, stream>>>(
      node_features, wnq_t, wto_t, bnq, vvec, b_out, (float*)d_out);
}